// Round 1
// baseline (446.052 us; speedup 1.0000x reference)
//
#include <hip/hip_runtime.h>

// Problem constants (fixed by setup_inputs)
#define N_  2
#define C_  12
#define D_  8
#define HG  16
#define WG  16
#define H_  2048
#define W_  2048
#define HW_ (H_*W_)

// Prepass: transpose grid [N,C,D,Hg,Wg] -> T [N,D,Hg,Wg,C]
// so the 12 channels of one (z,y,x) cell are contiguous (48 B, 16B-aligned).
__global__ __launch_bounds__(256) void transpose_grid_k(const float* __restrict__ g,
                                                        float* __restrict__ T) {
    int i = blockIdx.x * 256 + threadIdx.x;
    if (i >= N_ * C_ * D_ * HG * WG) return;
    int x = i & (WG - 1); int t = i >> 4;
    int y = t & (HG - 1); t >>= 4;
    int z = t & (D_ - 1); t >>= 3;
    int c = t % C_;
    int n = t / C_;
    T[(((n * D_ + z) * HG + y) * WG + x) * C_ + c] = g[i];
}

// One block = 1024 pixels of one image row (h uniform within block).
// x-interpolation folded into LDS staging.
// LDS layout: Lg[y][z][c]  (y-major!) -- z-stride = 12 floats = 48 B, so the
// 8 possible z-slots' 16-B reads tile all 32 banks exactly once. The wave's
// random-z gather is bank-conflict-free; y is wave-uniform (y*96 == 0 mod 32
// banks -> at most a free 2-way at y boundaries).
// Each thread: 4 pixels at stride 256 -> per-q stores are wave-contiguous.
__global__ __launch_bounds__(256) void slice_k(const float* __restrict__ T,
                                               const float* __restrict__ guide,
                                               float* __restrict__ out) {
    __shared__ float Lg[HG * D_ * C_];   // 6 KiB, [y][z][c]

    const int tid   = threadIdx.x;
    const int b     = blockIdx.x;
    const int wseg  = b & 1;             // which half of the row
    const int rowid = b >> 1;
    const int h     = rowid & (H_ - 1);
    const int n     = rowid >> 11;

    // ---- x interpolation factors (uniform across block) ----
    float xg   = (float)h / (H_ - 1) * 2.0f - 1.0f;
    float ixf  = (xg + 1.0f) * 0.5f * (WG - 1);
    float ix0f = floorf(ixf);
    float fx   = ixf - ix0f;
    int   x0   = (int)ix0f;
    int   x1   = x0 + 1;
    float wx0  = (1.0f - fx) * ((x0 >= 0 && x0 < WG) ? 1.0f : 0.0f);
    float wx1  = fx          * ((x1 >= 0 && x1 < WG) ? 1.0f : 0.0f);
    x0 = min(max(x0, 0), WG - 1);
    x1 = min(max(x1, 0), WG - 1);

    // ---- stage x-interpolated grid into LDS, layout [y][z][c] ----
    const float* Tn = T + n * (D_ * HG * WG * C_);
    for (int i = tid; i < D_ * HG * C_; i += 256) {
        int c  = i % C_;
        int yz = i / C_;                 // y*8 + z  (LDS-layout index)
        int z  = yz & (D_ - 1);
        int y  = yz >> 3;
        const float* s = Tn + (z * HG + y) * (WG * C_) + c;
        Lg[i] = wx0 * s[x0 * C_] + wx1 * s[x1 * C_];
    }
    __syncthreads();

    const int w0     = wseg * 1024;
    const int p_base = n * HW_ + h * W_ + w0 + tid;   // guide index, q=0
    const int o_base = n * (C_ * HW_) + h * W_ + w0 + tid;

#pragma unroll
    for (int q = 0; q < 4; ++q) {
        const int w = w0 + q * 256 + tid;
        const float gq = __builtin_nontemporal_load(guide + p_base + q * 256);

        // y interpolation
        float yg   = (float)w / (W_ - 1) * 2.0f - 1.0f;
        float iyf  = (yg + 1.0f) * 0.5f * (HG - 1);
        float iy0f = floorf(iyf);
        float fy   = iyf - iy0f;
        int   y0   = (int)iy0f, y1 = y0 + 1;
        float wy0  = (1.0f - fy) * ((y0 >= 0 && y0 < HG) ? 1.0f : 0.0f);
        float wy1  = fy          * ((y1 >= 0 && y1 < HG) ? 1.0f : 0.0f);
        y0 = min(max(y0, 0), HG - 1);
        y1 = min(max(y1, 0), HG - 1);

        // z interpolation (from guide)
        float izf  = (gq + 1.0f) * 0.5f * (D_ - 1);
        float iz0f = floorf(izf);
        float fz   = izf - iz0f;
        int   z0   = (int)iz0f, z1 = z0 + 1;
        float wz0  = (1.0f - fz) * ((z0 >= 0 && z0 < D_) ? 1.0f : 0.0f);
        float wz1  = fz          * ((z1 >= 0 && z1 < D_) ? 1.0f : 0.0f);
        z0 = min(max(z0, 0), D_ - 1);
        z1 = min(max(z1, 0), D_ - 1);

        // [y][z][c] layout: offset = (y*D_ + z)*C_
        const int o00 = (y0 * D_ + z0) * C_;   // pairs with w00 = wz0*wy0
        const int o01 = (y1 * D_ + z0) * C_;   // pairs with w01 = wz0*wy1
        const int o10 = (y0 * D_ + z1) * C_;   // pairs with w10 = wz1*wy0
        const int o11 = (y1 * D_ + z1) * C_;   // pairs with w11 = wz1*wy1
        const float w00 = wz0 * wy0, w01 = wz0 * wy1;
        const float w10 = wz1 * wy0, w11 = wz1 * wy1;

        const int ob = o_base + q * 256;
#pragma unroll
        for (int j = 0; j < 3; ++j) {
            float4 c00 = *(const float4*)(Lg + o00 + j * 4);
            float4 c01 = *(const float4*)(Lg + o01 + j * 4);
            float4 c10 = *(const float4*)(Lg + o10 + j * 4);
            float4 c11 = *(const float4*)(Lg + o11 + j * 4);
            float v0 = fmaf(w00, c00.x, fmaf(w01, c01.x, fmaf(w10, c10.x, w11 * c11.x)));
            float v1 = fmaf(w00, c00.y, fmaf(w01, c01.y, fmaf(w10, c10.y, w11 * c11.y)));
            float v2 = fmaf(w00, c00.z, fmaf(w01, c01.z, fmaf(w10, c10.z, w11 * c11.z)));
            float v3 = fmaf(w00, c00.w, fmaf(w01, c01.w, fmaf(w10, c10.w, w11 * c11.w)));
            __builtin_nontemporal_store(v0, out + ob + (j * 4 + 0) * HW_);
            __builtin_nontemporal_store(v1, out + ob + (j * 4 + 1) * HW_);
            __builtin_nontemporal_store(v2, out + ob + (j * 4 + 2) * HW_);
            __builtin_nontemporal_store(v3, out + ob + (j * 4 + 3) * HW_);
        }
    }
}

extern "C" void kernel_launch(void* const* d_in, const int* in_sizes, int n_in,
                              void* d_out, int out_size, void* d_ws, size_t ws_size,
                              hipStream_t stream) {
    const float* grid  = (const float*)d_in[0];  // [2,12,8,16,16]
    const float* guide = (const float*)d_in[1];  // [2,1,2048,2048]
    float* out = (float*)d_out;                  // [2,12,2048,2048]
    float* T   = (float*)d_ws;                   // 49152 floats = 192 KiB scratch

    hipLaunchKernelGGL(transpose_grid_k, dim3(192), dim3(256), 0, stream, grid, T);
    // blocks: 2 per row (1024 px each) x N*H rows
    hipLaunchKernelGGL(slice_k, dim3(N_ * H_ * 2), dim3(256), 0, stream,
                       T, guide, out);
}

// Round 3
// 426.867 us; speedup vs baseline: 1.0449x; 1.0449x over previous
//
#include <hip/hip_runtime.h>

// Problem constants (fixed by setup_inputs)
#define N_  2
#define C_  12
#define D_  8
#define HG  16
#define WG  16
#define H_  2048
#define W_  2048
#define HW_ (H_*W_)

// Native clang vector (HIP's float4 is a class -> rejected by
// __builtin_nontemporal_load/store; ext_vector_type is accepted).
typedef float f4 __attribute__((ext_vector_type(4)));

// Prepass: transpose grid [N,C,D,Hg,Wg] -> T [N,D,Hg,Wg,C]
// so the 12 channels of one (z,y,x) cell are contiguous (48 B, 16B-aligned).
__global__ __launch_bounds__(256) void transpose_grid_k(const float* __restrict__ g,
                                                        float* __restrict__ T) {
    int i = blockIdx.x * 256 + threadIdx.x;
    if (i >= N_ * C_ * D_ * HG * WG) return;
    int x = i & (WG - 1); int t = i >> 4;
    int y = t & (HG - 1); t >>= 4;
    int z = t & (D_ - 1); t >>= 3;
    int c = t % C_;
    int n = t / C_;
    T[(((n * D_ + z) * HG + y) * WG + x) * C_ + c] = g[i];
}

// One block = one full image row (2048 px). h uniform within block.
// x-interpolation folded into LDS staging; LDS layout Lg[y][z][c] (z-stride
// 48 B -> random-z gathers tile the banks).
// Each lane owns 4 CONSECUTIVE pixels: f4 guide load (16 B/lane),
// f4 nontemporal stores (12 per wave-pass instead of 48 dword stores),
// 4 independent guide->lds->fma chains per lane for latency hiding.
__global__ __launch_bounds__(256) void slice_k(const float* __restrict__ T,
                                               const float* __restrict__ guide,
                                               float* __restrict__ out) {
    __shared__ float Lg[HG * D_ * C_];   // 6 KiB, [y][z][c]

    const int tid = threadIdx.x;
    const int b   = blockIdx.x;          // [0, N_*H_)
    const int h   = b & (H_ - 1);
    const int n   = b >> 11;

    // ---- x interpolation factors (uniform across block) ----
    float xg   = (float)h / (H_ - 1) * 2.0f - 1.0f;
    float ixf  = (xg + 1.0f) * 0.5f * (WG - 1);
    float ix0f = floorf(ixf);
    float fx   = ixf - ix0f;
    int   x0   = (int)ix0f;
    int   x1   = x0 + 1;
    float wx0  = (1.0f - fx) * ((x0 >= 0 && x0 < WG) ? 1.0f : 0.0f);
    float wx1  = fx          * ((x1 >= 0 && x1 < WG) ? 1.0f : 0.0f);
    x0 = min(max(x0, 0), WG - 1);
    x1 = min(max(x1, 0), WG - 1);

    // ---- stage x-interpolated grid into LDS, layout [y][z][c] ----
    const float* Tn = T + n * (D_ * HG * WG * C_);
    for (int i = tid; i < D_ * HG * C_; i += 256) {
        int c  = i % C_;
        int yz = i / C_;                 // y*8 + z  (LDS-layout index)
        int z  = yz & (D_ - 1);
        int y  = yz >> 3;
        const float* s = Tn + (z * HG + y) * (WG * C_) + c;
        Lg[i] = wx0 * s[x0 * C_] + wx1 * s[x1 * C_];
    }
    __syncthreads();

    const int rowg = n * HW_ + h * W_;            // guide row base
    const int rowo = n * (C_ * HW_) + h * W_;     // out row base (channel 0)

    for (int q = 0; q < 2; ++q) {
        const int wbase = q * 1024 + tid * 4;     // first of this lane's 4 px
        const f4 g4 = __builtin_nontemporal_load(
            (const f4*)(guide + rowg + wbase));
        const float ga[4] = { g4.x, g4.y, g4.z, g4.w };

        float v[12][4];                           // [channel][pixel], static idx

#pragma unroll
        for (int p = 0; p < 4; ++p) {
            const int w = wbase + p;

            // y interpolation (varies per pixel)
            float yg   = (float)w / (W_ - 1) * 2.0f - 1.0f;
            float iyf  = (yg + 1.0f) * 0.5f * (HG - 1);
            float iy0f = floorf(iyf);
            float fy   = iyf - iy0f;
            int   y0   = (int)iy0f, y1 = y0 + 1;
            float wy0  = (1.0f - fy) * ((y0 >= 0 && y0 < HG) ? 1.0f : 0.0f);
            float wy1  = fy          * ((y1 >= 0 && y1 < HG) ? 1.0f : 0.0f);
            y0 = min(max(y0, 0), HG - 1);
            y1 = min(max(y1, 0), HG - 1);

            // z interpolation (from guide)
            float gq   = ga[p];
            float izf  = (gq + 1.0f) * 0.5f * (D_ - 1);
            float iz0f = floorf(izf);
            float fz   = izf - iz0f;
            int   z0   = (int)iz0f, z1 = z0 + 1;
            float wz0  = (1.0f - fz) * ((z0 >= 0 && z0 < D_) ? 1.0f : 0.0f);
            float wz1  = fz          * ((z1 >= 0 && z1 < D_) ? 1.0f : 0.0f);
            z0 = min(max(z0, 0), D_ - 1);
            z1 = min(max(z1, 0), D_ - 1);

            // [y][z][c] layout: offset = (y*D_ + z)*C_
            const int o00 = (y0 * D_ + z0) * C_;   // w00 = wz0*wy0
            const int o01 = (y1 * D_ + z0) * C_;   // w01 = wz0*wy1
            const int o10 = (y0 * D_ + z1) * C_;   // w10 = wz1*wy0
            const int o11 = (y1 * D_ + z1) * C_;   // w11 = wz1*wy1
            const float w00 = wz0 * wy0, w01 = wz0 * wy1;
            const float w10 = wz1 * wy0, w11 = wz1 * wy1;

#pragma unroll
            for (int j = 0; j < 3; ++j) {
                f4 c00 = *(const f4*)(Lg + o00 + j * 4);
                f4 c01 = *(const f4*)(Lg + o01 + j * 4);
                f4 c10 = *(const f4*)(Lg + o10 + j * 4);
                f4 c11 = *(const f4*)(Lg + o11 + j * 4);
                v[j * 4 + 0][p] = fmaf(w00, c00.x, fmaf(w01, c01.x, fmaf(w10, c10.x, w11 * c11.x)));
                v[j * 4 + 1][p] = fmaf(w00, c00.y, fmaf(w01, c01.y, fmaf(w10, c10.y, w11 * c11.y)));
                v[j * 4 + 2][p] = fmaf(w00, c00.z, fmaf(w01, c01.z, fmaf(w10, c10.z, w11 * c11.z)));
                v[j * 4 + 3][p] = fmaf(w00, c00.w, fmaf(w01, c01.w, fmaf(w10, c10.w, w11 * c11.w)));
            }
        }

        // 12 f4 nontemporal stores: 1 KiB per wave per instruction
#pragma unroll
        for (int c = 0; c < 12; ++c) {
            f4 o = { v[c][0], v[c][1], v[c][2], v[c][3] };
            __builtin_nontemporal_store(o, (f4*)(out + rowo + c * HW_ + wbase));
        }
    }
}

extern "C" void kernel_launch(void* const* d_in, const int* in_sizes, int n_in,
                              void* d_out, int out_size, void* d_ws, size_t ws_size,
                              hipStream_t stream) {
    const float* grid  = (const float*)d_in[0];  // [2,12,8,16,16]
    const float* guide = (const float*)d_in[1];  // [2,1,2048,2048]
    float* out = (float*)d_out;                  // [2,12,2048,2048]
    float* T   = (float*)d_ws;                   // 49152 floats = 192 KiB scratch

    hipLaunchKernelGGL(transpose_grid_k, dim3(192), dim3(256), 0, stream, grid, T);
    // one block per image row
    hipLaunchKernelGGL(slice_k, dim3(N_ * H_), dim3(256), 0, stream,
                       T, guide, out);
}

// Round 4
// 424.888 us; speedup vs baseline: 1.0498x; 1.0047x over previous
//
#include <hip/hip_runtime.h>

// Problem constants (fixed by setup_inputs)
#define N_  2
#define C_  12
#define D_  8
#define HG  16
#define WG  16
#define H_  2048
#define W_  2048
#define HW_ (H_*W_)

// Native clang vector (HIP's float4 is a class -> rejected by
// __builtin_nontemporal_load/store; ext_vector_type is accepted).
typedef float f4 __attribute__((ext_vector_type(4)));

// Prepass: transpose grid [N,C,D,Hg,Wg] -> T [N,D,Hg,Wg,C]
// so the 12 channels of one (z,y,x) cell are contiguous (48 B, 16B-aligned).
__global__ __launch_bounds__(256) void transpose_grid_k(const float* __restrict__ g,
                                                        float* __restrict__ T) {
    int i = blockIdx.x * 256 + threadIdx.x;
    if (i >= N_ * C_ * D_ * HG * WG) return;
    int x = i & (WG - 1); int t = i >> 4;
    int y = t & (HG - 1); t >>= 4;
    int z = t & (D_ - 1); t >>= 3;
    int c = t % C_;
    int n = t / C_;
    T[(((n * D_ + z) * HG + y) * WG + x) * C_ + c] = g[i];
}

// One block = one full image row (2048 px). h uniform within block.
// Latency-oriented structure:
//  - both guide f4 NT loads issued BEFORE LDS staging (their ~900cy HBM
//    latency hides under staging + barrier)
//  - j-outer/p-inner compute with per-j f4 stores: output live range 16
//    floats instead of 48 -> VGPR down
//  - __launch_bounds__(256,4): cap VGPR at 128 -> 16 waves/CU
//  - x,y interp validity multiplies dropped (coords from linspace are
//    provably in-range; boundary weight is exactly 0); z keeps full masks.
// LDS layout Lg[y][z][c]: z-stride 48 B -> random-z b128 gathers tile banks.
__global__ __launch_bounds__(256, 4) void slice_k(const float* __restrict__ T,
                                                  const float* __restrict__ guide,
                                                  float* __restrict__ out) {
    __shared__ float Lg[HG * D_ * C_];   // 6 KiB, [y][z][c]

    const int tid = threadIdx.x;
    const int b   = blockIdx.x;          // [0, N_*H_)
    const int h   = b & (H_ - 1);
    const int n   = b >> 11;

    const int rowg = n * HW_ + h * W_;            // guide row base
    const int rowo = n * (C_ * HW_) + h * W_;     // out row base (channel 0)

    // ---- guide prefetch: issue both segments' loads up front ----
    const f4 g0 = __builtin_nontemporal_load((const f4*)(guide + rowg + tid * 4));
    const f4 g1 = __builtin_nontemporal_load((const f4*)(guide + rowg + 1024 + tid * 4));

    // ---- x interpolation factors (uniform across block) ----
    float xg   = (float)h / (H_ - 1) * 2.0f - 1.0f;
    float ixf  = (xg + 1.0f) * 0.5f * (WG - 1);   // in [0,15] exactly
    float ix0f = floorf(ixf);
    float fx   = ixf - ix0f;
    int   x0   = (int)ix0f;
    int   x1   = min(x0 + 1, WG - 1);             // x0=15 only when fx==0
    float wx0  = 1.0f - fx;
    float wx1  = fx;

    // ---- stage x-interpolated grid into LDS, layout [y][z][c] ----
    const float* Tn = T + n * (D_ * HG * WG * C_);
    for (int i = tid; i < D_ * HG * C_; i += 256) {
        int c  = i % C_;
        int yz = i / C_;                 // y*8 + z  (LDS-layout index)
        int z  = yz & (D_ - 1);
        int y  = yz >> 3;
        const float* s = Tn + (z * HG + y) * (WG * C_) + c;
        Lg[i] = wx0 * s[x0 * C_] + wx1 * s[x1 * C_];
    }
    __syncthreads();

    auto process = [&](f4 g4, int wbase) {
        const float ga[4] = { g4.x, g4.y, g4.z, g4.w };

        // per-pixel weights + LDS offsets (static-indexed arrays -> regs)
        float w00a[4], w01a[4], w10a[4], w11a[4];
        int   o00a[4], o01a[4], o10a[4], o11a[4];

#pragma unroll
        for (int p = 0; p < 4; ++p) {
            const int w = wbase + p;

            // y interpolation: iyf = w * 15/2047, provably in [0,15]
            float iyf  = (float)w * ((float)(HG - 1) / (float)(W_ - 1));
            float iy0f = floorf(iyf);
            float fy   = iyf - iy0f;
            int   y0   = (int)iy0f;
            int   y1   = min(y0 + 1, HG - 1);     // y0=15 only when fy==0
            float wy0  = 1.0f - fy;
            float wy1  = fy;

            // z interpolation (data-dependent; keep full validity masks)
            float izf  = fmaf(ga[p], 0.5f * (D_ - 1), 0.5f * (D_ - 1));
            float iz0f = floorf(izf);
            float fz   = izf - iz0f;
            int   z0   = (int)iz0f, z1 = z0 + 1;
            float wz0  = (1.0f - fz) * ((z0 >= 0 && z0 < D_) ? 1.0f : 0.0f);
            float wz1  = fz          * ((z1 >= 0 && z1 < D_) ? 1.0f : 0.0f);
            z0 = min(max(z0, 0), D_ - 1);
            z1 = min(max(z1, 0), D_ - 1);

            // [y][z][c] layout: offset = (y*D_ + z)*C_
            o00a[p] = (y0 * D_ + z0) * C_;        // wz0*wy0
            o01a[p] = (y1 * D_ + z0) * C_;        // wz0*wy1
            o10a[p] = (y0 * D_ + z1) * C_;        // wz1*wy0
            o11a[p] = (y1 * D_ + z1) * C_;        // wz1*wy1
            w00a[p] = wz0 * wy0;
            w01a[p] = wz0 * wy1;
            w10a[p] = wz1 * wy0;
            w11a[p] = wz1 * wy1;
        }

        float* outp = out + rowo + wbase;

#pragma unroll
        for (int j = 0; j < 3; ++j) {
            f4 t[4];                              // [pixel], static idx
#pragma unroll
            for (int p = 0; p < 4; ++p) {
                f4 c00 = *(const f4*)(Lg + o00a[p] + j * 4);
                f4 c01 = *(const f4*)(Lg + o01a[p] + j * 4);
                f4 c10 = *(const f4*)(Lg + o10a[p] + j * 4);
                f4 c11 = *(const f4*)(Lg + o11a[p] + j * 4);
                f4 v;
                v.x = fmaf(w00a[p], c00.x, fmaf(w01a[p], c01.x, fmaf(w10a[p], c10.x, w11a[p] * c11.x)));
                v.y = fmaf(w00a[p], c00.y, fmaf(w01a[p], c01.y, fmaf(w10a[p], c10.y, w11a[p] * c11.y)));
                v.z = fmaf(w00a[p], c00.z, fmaf(w01a[p], c01.z, fmaf(w10a[p], c10.z, w11a[p] * c11.z)));
                v.w = fmaf(w00a[p], c00.w, fmaf(w01a[p], c01.w, fmaf(w10a[p], c10.w, w11a[p] * c11.w)));
                t[p] = v;
            }
            // transpose 4x4 in regs: channel k across the lane's 4 pixels
#pragma unroll
            for (int k = 0; k < 4; ++k) {
                f4 o = { t[0][k], t[1][k], t[2][k], t[3][k] };
                __builtin_nontemporal_store(o, (f4*)(outp + (j * 4 + k) * HW_));
            }
        }
    };

    process(g0, tid * 4);
    process(g1, 1024 + tid * 4);
}

extern "C" void kernel_launch(void* const* d_in, const int* in_sizes, int n_in,
                              void* d_out, int out_size, void* d_ws, size_t ws_size,
                              hipStream_t stream) {
    const float* grid  = (const float*)d_in[0];  // [2,12,8,16,16]
    const float* guide = (const float*)d_in[1];  // [2,1,2048,2048]
    float* out = (float*)d_out;                  // [2,12,2048,2048]
    float* T   = (float*)d_ws;                   // 49152 floats = 192 KiB scratch

    hipLaunchKernelGGL(transpose_grid_k, dim3(192), dim3(256), 0, stream, grid, T);
    // one block per image row
    hipLaunchKernelGGL(slice_k, dim3(N_ * H_), dim3(256), 0, stream,
                       T, guide, out);
}